// Round 5
// baseline (347.021 us; speedup 1.0000x reference)
//
#include <hip/hip_runtime.h>
#include <math.h>

#define IDIM 2048
#define NE   64
#define TOPK 8
#define NB   16384
#define TM   32            // rows per block
#define DK   16            // K per staging tile
#define KT   512           // K per team
#define LSX  20            // LDS row stride (floats) = DK + 4
#define TAU  5e-4f

// ws float layout: [0..63] f counts, [64..127] p sums, [128] z sum,
//                  [129] (int) flag count, [130..] (int) flagged row list
#define WS_CNT 129
#define WS_LIST 130

__device__ __forceinline__ float softplusf(float v) {
    return (v > 0.f) ? (v + log1pf(expf(-v))) : log1pf(expf(v));
}
__device__ __forceinline__ double softplus_d(double v) {
    return (v > 0.0) ? (v + log1p(exp(-v))) : log1p(exp(v));
}

__global__ void init_ws_kernel(float* ws) {
    int t = threadIdx.x;
    if (t < WS_LIST) ws[t] = 0.0f;
}

// ---------------- pass 1: fp32 GEMM + gating + flag near-ties ----------------
// LDS float map (12929 floats = 51.7 KB):
//   staging: team*3200: sX[32][20], sWg[64][20] @+640, sWn[64][20] @+1920
//   alias after main loop: xfer[384][17] @0 (6528 f)
//                          sLogF[32][66] @6528, sNoisyF[32][66] @8640
//   sP @12800, sF @12864, sZ @12928
__global__ __launch_bounds__(512, 2) void gate_main_kernel(
    const float* __restrict__ x, const float* __restrict__ noise,
    const float* __restrict__ Wg, const float* __restrict__ bg,
    const float* __restrict__ Wn,
    float* __restrict__ out_w, float* __restrict__ out_i,
    float* __restrict__ ws, int listCap)
{
    __shared__ float smf[12929];

    const int t    = threadIdx.x;
    const int team = t >> 7;          // 0..3 (K quarter)
    const int lt   = t & 127;
    const int expcol = lt & 15;       // experts expcol + 16m, m=0..3
    const int rowg   = lt >> 4;       // rows rowg + 8j, j=0..3
    const int row0 = blockIdx.x * TM;

    float* stg = smf + team * 3200;
    float* sX  = stg;
    float* sWg = stg + 640;
    float* sWn = stg + 1920;
    float* xfer    = smf;             // [384][17]
    float* sLogF   = smf + 6528;      // [32][66]
    float* sNoisyF = smf + 8640;      // [32][66]
    float* sP = smf + 12800;
    float* sF = smf + 12864;
    float* sZ = smf + 12928;

    if (t < NE) { sP[t] = 0.f; sF[t] = 0.f; }
    if (t == 0) sZ[0] = 0.f;

    float accg[4][4], accn[4][4];
    #pragma unroll
    for (int j = 0; j < 4; ++j)
        #pragma unroll
        for (int m = 0; m < 4; ++m) { accg[j][m] = 0.f; accn[j][m] = 0.f; }

    // staging: 5 float4 per thread per tile
    const int lr = lt >> 2;           // 0..31
    const int wc = (lt & 3) * 4;      // 0,4,8,12
    const float* xp  = x  + (size_t)(row0 + lr) * IDIM + team * KT + wc;
    const float* gp0 = Wg + (size_t)lr        * IDIM + team * KT + wc;
    const float* gp1 = Wg + (size_t)(lr + 32) * IDIM + team * KT + wc;
    const float* np0 = Wn + (size_t)lr        * IDIM + team * KT + wc;
    const float* np1 = Wn + (size_t)(lr + 32) * IDIM + team * KT + wc;

    float4 va, vb, vc, vd, ve;   // in-flight staging tile

#define ISSUE(k0) { \
    va = *(const float4*)(xp  + (k0)); \
    vb = *(const float4*)(gp0 + (k0)); \
    vc = *(const float4*)(gp1 + (k0)); \
    vd = *(const float4*)(np0 + (k0)); \
    ve = *(const float4*)(np1 + (k0)); }

    ISSUE(0);

    for (int tile = 0; tile < KT / DK; ++tile) {
        __syncthreads();   // previous tile's LDS reads complete
        *(float4*)&sX [lr * LSX + wc]        = va;
        *(float4*)&sWg[lr * LSX + wc]        = vb;
        *(float4*)&sWg[(lr + 32) * LSX + wc] = vc;
        *(float4*)&sWn[lr * LSX + wc]        = vd;
        *(float4*)&sWn[(lr + 32) * LSX + wc] = ve;
        __syncthreads();   // writes visible

        // prefetch NEXT tile: latency hides under this tile's FMAs
        if (tile + 1 < KT / DK) ISSUE((tile + 1) * DK);

        #pragma unroll
        for (int kk = 0; kk < DK; kk += 4) {
            float4 xv[4], gv[4], nv[4];
            #pragma unroll
            for (int j = 0; j < 4; ++j)
                xv[j] = *(const float4*)&sX[(rowg + 8 * j) * LSX + kk];
            #pragma unroll
            for (int m = 0; m < 4; ++m) {
                gv[m] = *(const float4*)&sWg[(expcol + 16 * m) * LSX + kk];
                nv[m] = *(const float4*)&sWn[(expcol + 16 * m) * LSX + kk];
            }
            #pragma unroll
            for (int q = 0; q < 4; ++q) {
                float gq[4], nq[4];
                #pragma unroll
                for (int m = 0; m < 4; ++m) { gq[m] = ((float*)&gv[m])[q]; nq[m] = ((float*)&nv[m])[q]; }
                #pragma unroll
                for (int j = 0; j < 4; ++j) {
                    float xq = ((float*)&xv[j])[q];
                    #pragma unroll
                    for (int m = 0; m < 4; ++m) {
                        accg[j][m] = fmaf(xq, gq[m], accg[j][m]);
                        accn[j][m] = fmaf(xq, nq[m], accn[j][m]);
                    }
                }
            }
        }
    }
    __syncthreads();   // staging dead; safe to alias

    // ---- combine 4 teams: phase A (logits), phase B (noise pre-act) ----
    if (team != 0) {
        float* xf = xfer + ((team - 1) * 128 + lt) * 17;
        #pragma unroll
        for (int j = 0; j < 4; ++j)
            #pragma unroll
            for (int m = 0; m < 4; ++m) xf[j * 4 + m] = accg[j][m];
    }
    __syncthreads();
    if (team == 0) {
        #pragma unroll
        for (int j = 0; j < 4; ++j) {
            int r = rowg + 8 * j;
            #pragma unroll
            for (int m = 0; m < 4; ++m) {
                int e = expcol + 16 * m;
                float g = accg[j][m]
                        + xfer[(lt) * 17 + j * 4 + m]
                        + xfer[(128 + lt) * 17 + j * 4 + m]
                        + xfer[(256 + lt) * 17 + j * 4 + m];
                sLogF[r * 66 + e] = g + bg[e];
            }
        }
    }
    __syncthreads();
    if (team != 0) {
        float* xf = xfer + ((team - 1) * 128 + lt) * 17;
        #pragma unroll
        for (int j = 0; j < 4; ++j)
            #pragma unroll
            for (int m = 0; m < 4; ++m) xf[j * 4 + m] = accn[j][m];
    }
    __syncthreads();
    if (team == 0) {
        #pragma unroll
        for (int j = 0; j < 4; ++j) {
            int r = rowg + 8 * j;
            int grow = row0 + r;
            #pragma unroll
            for (int m = 0; m < 4; ++m) {
                int e = expcol + 16 * m;
                float n = accn[j][m]
                        + xfer[(lt) * 17 + j * 4 + m]
                        + xfer[(128 + lt) * 17 + j * 4 + m]
                        + xfer[(256 + lt) * 17 + j * 4 + m];
                float sp = softplusf(n);
                float nz = noise[(size_t)grow * NE + e];
                sNoisyF[r * 66 + e] = fmaf(nz, sp, sLogF[r * 66 + e]);
            }
        }
    }
    __syncthreads();

    // ---- wave-parallel epilogue: 8 waves x 4 rows, lane = expert ----
    const int wv = t >> 6, lane = t & 63;
    float pacc = 0.f, zacc = 0.f;

    #pragma unroll 1
    for (int rr = 0; rr < 4; ++rr) {
        const int r = wv * 4 + rr;
        const int grow = row0 + r;
        float vcur = sNoisyF[r * 66 + lane];
        float lg   = sLogF[r * 66 + lane];

        float tkv[9]; int tki[9];
        #pragma unroll
        for (int k = 0; k < 9; ++k) {
            float mv = vcur; int mi = lane;
            #pragma unroll
            for (int o = 32; o > 0; o >>= 1) {
                float ov = __shfl_xor(mv, o);
                int   oi = __shfl_xor(mi, o);
                if (ov > mv || (ov == mv && oi < mi)) { mv = ov; mi = oi; }
            }
            tkv[k] = mv; tki[k] = mi;
            if (lane == mi) vcur = -1e30f;
        }

        float m0 = tkv[0], s = 0.f, w[TOPK];
        #pragma unroll
        for (int k = 0; k < TOPK; ++k) { w[k] = expf(tkv[k] - m0); s += w[k]; }
        float inv = 1.f / s;
        float myw = 0.f; int myi = 0;
        #pragma unroll
        for (int k = 0; k < TOPK; ++k)
            if (lane == k) { myw = w[k] * inv; myi = tki[k]; }
        if (lane < TOPK) {
            out_w[(size_t)grow * TOPK + lane] = myw;
            out_i[(size_t)grow * TOPK + lane] = (float)myi;
        }

        if (lane == 0) {
            atomicAdd(&sF[tki[0]], 1.f);
            float ming = 1e30f;
            #pragma unroll
            for (int k = 0; k < 8; ++k) ming = fminf(ming, tkv[k] - tkv[k + 1]);
            if (ming < TAU) {
                int slot = atomicAdd((int*)&ws[WS_CNT], 1);
                if (slot < listCap) ((int*)ws)[WS_LIST + slot] = grow;
            }
        }

        float rm = lg;
        #pragma unroll
        for (int o = 32; o > 0; o >>= 1) rm = fmaxf(rm, __shfl_xor(rm, o));
        float pe = expf(lg - rm);
        float ssum = pe;
        #pragma unroll
        for (int o = 32; o > 0; o >>= 1) ssum += __shfl_xor(ssum, o);
        pacc += pe / ssum;
        if (lane == 0) { float lse = rm + logf(ssum); zacc += lse * lse; }
    }

    atomicAdd(&sP[lane], pacc);
    if (lane == 0) atomicAdd(sZ, zacc);
    __syncthreads();
    if (t < NE) {
        atomicAdd(&ws[t],      sF[t]);
        atomicAdd(&ws[NE + t], sP[t]);
    }
    if (t == 0) atomicAdd(&ws[2 * NE], sZ[0]);
}

// ---------------- pass 2: fp64 recheck of flagged rows ----------------
__global__ __launch_bounds__(256) void recheck_kernel(
    const float* __restrict__ x, const float* __restrict__ noise,
    const float* __restrict__ Wg, const float* __restrict__ bg,
    const float* __restrict__ Wn,
    float* __restrict__ out_w, float* __restrict__ out_i,
    const float* __restrict__ ws, int listCap)
{
    __shared__ double sRed[256 * 4];
    const int* wsi = (const int*)ws;
    int cnt = wsi[WS_CNT];
    if (cnt > listCap) cnt = listCap;
    if (cnt <= 0) return;

    const int t = threadIdx.x;
    const int e128 = t & 127;         // 0..63: Wg expert; 64..127: Wn expert-64
    const int half = t >> 7;          // K half

    const float* wr = (e128 < 64) ? (Wg + (size_t)e128 * IDIM)
                                  : (Wn + (size_t)(e128 - 64) * IDIM);
    wr += half * 1024;

    for (int base = blockIdx.x * 4; base < cnt; base += gridDim.x * 4) {
        int rows[4];
        #pragma unroll
        for (int i = 0; i < 4; ++i) {
            int ii = base + i;
            rows[i] = wsi[WS_LIST + (ii < cnt ? ii : cnt - 1)];
        }
        const float* xr0 = x + (size_t)rows[0] * IDIM + half * 1024;
        const float* xr1 = x + (size_t)rows[1] * IDIM + half * 1024;
        const float* xr2 = x + (size_t)rows[2] * IDIM + half * 1024;
        const float* xr3 = x + (size_t)rows[3] * IDIM + half * 1024;

        double a0 = 0, a1 = 0, a2 = 0, a3 = 0;
        for (int k = 0; k < 1024; k += 4) {
            float4 wv = *(const float4*)(wr + k);
            float4 x0 = *(const float4*)(xr0 + k);
            float4 x1 = *(const float4*)(xr1 + k);
            float4 x2 = *(const float4*)(xr2 + k);
            float4 x3 = *(const float4*)(xr3 + k);
            #pragma unroll
            for (int q = 0; q < 4; ++q) {
                double wd = (double)((float*)&wv)[q];
                a0 = fma((double)((float*)&x0)[q], wd, a0);
                a1 = fma((double)((float*)&x1)[q], wd, a1);
                a2 = fma((double)((float*)&x2)[q], wd, a2);
                a3 = fma((double)((float*)&x3)[q], wd, a3);
            }
        }
        sRed[t * 4 + 0] = a0; sRed[t * 4 + 1] = a1;
        sRed[t * 4 + 2] = a2; sRed[t * 4 + 3] = a3;
        __syncthreads();
        if (t < 128) {
            #pragma unroll
            for (int i = 0; i < 4; ++i) sRed[t * 4 + i] += sRed[(t + 128) * 4 + i];
        }
        __syncthreads();
        if (t < 64) {
            const int lane = t;
            double bgl = (double)bg[lane];
            #pragma unroll 1
            for (int i = 0; i < 4; ++i) {
                int row = rows[i];
                double g = sRed[lane * 4 + i];
                double n = sRed[(64 + lane) * 4 + i];
                double lg = g + bgl;
                double nz = (double)noise[(size_t)row * NE + lane];
                double vcur = fma(nz, softplus_d(n), lg);

                double tkv[TOPK]; int tki[TOPK];
                #pragma unroll
                for (int k = 0; k < TOPK; ++k) {
                    double mv = vcur; int mi = lane;
                    #pragma unroll
                    for (int o = 32; o > 0; o >>= 1) {
                        double ov = __shfl_xor(mv, o);
                        int    oi = __shfl_xor(mi, o);
                        if (ov > mv || (ov == mv && oi < mi)) { mv = ov; mi = oi; }
                    }
                    tkv[k] = mv; tki[k] = mi;
                    if (lane == mi) vcur = -1e300;
                }
                double m0 = tkv[0], s = 0.0, wk[TOPK];
                #pragma unroll
                for (int k = 0; k < TOPK; ++k) { wk[k] = exp(tkv[k] - m0); s += wk[k]; }
                double inv = 1.0 / s;
                float myw = 0.f; int myi = 0;
                #pragma unroll
                for (int k = 0; k < TOPK; ++k)
                    if (lane == k) { myw = (float)(wk[k] * inv); myi = tki[k]; }
                if (lane < TOPK) {
                    out_w[(size_t)row * TOPK + lane] = myw;
                    out_i[(size_t)row * TOPK + lane] = (float)myi;
                }
            }
        }
        __syncthreads();
    }
}

__global__ void finalize_kernel(const float* __restrict__ ws, float* __restrict__ out) {
    int t = threadIdx.x; // 64 threads, one wave
    float v = (ws[t] / (float)NB) * (ws[NE + t] / (float)NB);
    #pragma unroll
    for (int o = 32; o > 0; o >>= 1) v += __shfl_down(v, o);
    if (t == 0) {
        out[2 * NB * TOPK]     = (float)NE * v;
        out[2 * NB * TOPK + 1] = ws[2 * NE] / (float)NB;
    }
}

extern "C" void kernel_launch(void* const* d_in, const int* in_sizes, int n_in,
                              void* d_out, int out_size, void* d_ws, size_t ws_size,
                              hipStream_t stream) {
    const float* x     = (const float*)d_in[0];
    const float* noise = (const float*)d_in[1];
    const float* Wg    = (const float*)d_in[2];
    const float* bg    = (const float*)d_in[3];
    const float* Wn    = (const float*)d_in[4];
    float* out = (float*)d_out;
    float* ws  = (float*)d_ws;

    long cap = (long)(ws_size / 4) - WS_LIST;
    int listCap = (int)(cap < 0 ? 0 : (cap > NB ? NB : cap));

    hipLaunchKernelGGL(init_ws_kernel, dim3(1), dim3(256), 0, stream, ws);
    hipLaunchKernelGGL(gate_main_kernel, dim3(NB / TM), dim3(512), 0, stream,
                       x, noise, Wg, bg, Wn,
                       out, out + (size_t)NB * TOPK, ws, listCap);
    hipLaunchKernelGGL(recheck_kernel, dim3(256), dim3(256), 0, stream,
                       x, noise, Wg, bg, Wn,
                       out, out + (size_t)NB * TOPK, ws, listCap);
    hipLaunchKernelGGL(finalize_kernel, dim3(1), dim3(64), 0, stream, ws, out);
}

// Round 6
// 219.968 us; speedup vs baseline: 1.5776x; 1.5776x over previous
//
#include <hip/hip_runtime.h>
#include <math.h>

#define IDIM 2048
#define NE   64
#define TOPK 8
#define NB   16384
#define BM   32            // rows per block
#define BK   64            // k per chunk
#define NCH  (IDIM / BK)   // 32 chunks
#define TAU  5e-4f

// ws float layout: [0..63] f counts, [64..127] p sums, [128] z sum,
//                  [129] (int) flag count, [130..] (int) flagged row list
#define WS_CNT 129
#define WS_LIST 130

typedef __attribute__((ext_vector_type(8))) short bf16x8_t;  // 8 bf16 = 4 VGPRs
typedef __attribute__((ext_vector_type(4))) float f32x4_t;   // MFMA acc

__device__ __forceinline__ float softplusf(float v) {
    return (v > 0.f) ? (v + log1pf(expf(-v))) : log1pf(expf(v));
}
__device__ __forceinline__ double softplus_d(double v) {
    return (v > 0.0) ? (v + log1p(exp(-v))) : log1p(exp(v));
}

// deterministic RNE fp32 -> bf16 bits (bit-exact every call)
__device__ __forceinline__ short f2bf(float f) {
    unsigned u = __float_as_uint(f);
    unsigned r = (u + 0x7FFFu + ((u >> 16) & 1u)) >> 16;
    return (short)r;
}
__device__ __forceinline__ float bf2f(short s) {
    return __uint_as_float(((unsigned)(unsigned short)s) << 16);
}

__global__ void init_ws_kernel(float* ws) {
    int t = threadIdx.x;
    if (t < WS_LIST) ws[t] = 0.0f;
}

// convert 8 f32 -> hi/lo bf16 slots and store as two b128 LDS writes
__device__ __forceinline__ void cvt_slot(const float4 v0, const float4 v1,
                                         char* hiP, char* loP, int off) {
    float fv[8] = {v0.x, v0.y, v0.z, v0.w, v1.x, v1.y, v1.z, v1.w};
    bf16x8_t H, L;
    #pragma unroll
    for (int q = 0; q < 8; ++q) {
        short hb = f2bf(fv[q]);
        short lb = f2bf(fv[q] - bf2f(hb));
        H[q] = hb; L[q] = lb;
    }
    *(bf16x8_t*)(hiP + off) = H;
    *(bf16x8_t*)(loP + off) = L;
}

// ---------------- pass 1: split-bf16 MFMA GEMM + gating + flag near-ties ----------------
// LDS map (bytes): AH@0 (4096) AL@4096 (4096) BH@8192 (16384) BL@24576 (16384)
//   epilogue alias: sL f32[32][132] @0 (16896)
//   sP@40960 sF@41216 sZ@41472
__global__ __launch_bounds__(256, 2) void gate_main_kernel(
    const float* __restrict__ x, const float* __restrict__ noise,
    const float* __restrict__ Wg, const float* __restrict__ bg,
    const float* __restrict__ Wn,
    float* __restrict__ out_w, float* __restrict__ out_i,
    float* __restrict__ ws, int listCap)
{
    __shared__ char smem[41488] __attribute__((aligned(16)));
    char* AH = smem;
    char* AL = smem + 4096;
    char* BH = smem + 8192;
    char* BL = smem + 24576;
    float* sP = (float*)(smem + 40960);
    float* sF = (float*)(smem + 41216);
    float* sZ = (float*)(smem + 41472);
    float* sL = (float*)smem;            // [32][132] epilogue alias

    const int u   = threadIdx.x;
    const int w   = u >> 6;              // wave 0..3, owns cols [w*32, w*32+32)
    const int l   = u & 63;
    const int lr  = l & 15;
    const int lg4 = l >> 4;
    const int s7  = lr & 7;
    const int row0 = blockIdx.x * BM;

    if (u < NE) { sP[u] = 0.f; sF[u] = 0.f; }
    if (u == 0) sZ[0] = 0.f;

    // staging geometry: thread -> (row = u>>3, 16B-slot col = u&7)
    const int ar = u >> 3;               // 0..31
    const int ac = u & 7;                // 0..7
    const int wsl  = ((ac ^ (ar & 7)) << 4);   // XOR-swizzled 16B slot
    const int aoff = ar * 128 + wsl;
    const int boff = ar * 128 + wsl;

    const float* pa  = x  + (size_t)(row0 + ar) * IDIM + ac * 8;
    const float* pb0 = Wg + (size_t)ar        * IDIM + ac * 8;
    const float* pb1 = Wg + (size_t)(ar + 32) * IDIM + ac * 8;
    const float* pb2 = Wn + (size_t)ar        * IDIM + ac * 8;
    const float* pb3 = Wn + (size_t)(ar + 32) * IDIM + ac * 8;

    f32x4_t acc[2][2];
    #pragma unroll
    for (int mt = 0; mt < 2; ++mt)
        #pragma unroll
        for (int nt = 0; nt < 2; ++nt) {
            f32x4_t z = {0.f, 0.f, 0.f, 0.f};
            acc[mt][nt] = z;
        }

    float4 ra0, ra1, rb0, rb1, rb2, rb3, rb4, rb5, rb6, rb7;
#define LOADT(t) { const int k0 = (t) * BK; \
    ra0 = *(const float4*)(pa  + k0); ra1 = *(const float4*)(pa  + k0 + 4); \
    rb0 = *(const float4*)(pb0 + k0); rb1 = *(const float4*)(pb0 + k0 + 4); \
    rb2 = *(const float4*)(pb1 + k0); rb3 = *(const float4*)(pb1 + k0 + 4); \
    rb4 = *(const float4*)(pb2 + k0); rb5 = *(const float4*)(pb2 + k0 + 4); \
    rb6 = *(const float4*)(pb3 + k0); rb7 = *(const float4*)(pb3 + k0 + 4); }

    LOADT(0);

    for (int t = 0; t < NCH; ++t) {
        cvt_slot(ra0, ra1, AH, AL, aoff);
        cvt_slot(rb0, rb1, BH, BL, boff);
        cvt_slot(rb2, rb3, BH, BL, boff + 4096);
        cvt_slot(rb4, rb5, BH, BL, boff + 8192);
        cvt_slot(rb6, rb7, BH, BL, boff + 12288);
        if (t + 1 < NCH) LOADT(t + 1);   // issue early; lands during compute
        __syncthreads();                 // staging visible

        #pragma unroll
        for (int ks = 0; ks < 2; ++ks) {
            const int so = (((ks * 4 + lg4) ^ s7) << 4);
            bf16x8_t ah[2], al_[2], bh[2], bl[2];
            #pragma unroll
            for (int mt = 0; mt < 2; ++mt) {
                const int o = (mt * 16 + lr) * 128 + so;
                ah[mt]  = *(const bf16x8_t*)(AH + o);
                al_[mt] = *(const bf16x8_t*)(AL + o);
            }
            #pragma unroll
            for (int nt = 0; nt < 2; ++nt) {
                const int o = (w * 32 + nt * 16 + lr) * 128 + so;
                bh[nt] = *(const bf16x8_t*)(BH + o);
                bl[nt] = *(const bf16x8_t*)(BL + o);
            }
            #pragma unroll
            for (int mt = 0; mt < 2; ++mt)
                #pragma unroll
                for (int nt = 0; nt < 2; ++nt)
                    acc[mt][nt] = __builtin_amdgcn_mfma_f32_16x16x32_bf16(ah[mt], bh[nt], acc[mt][nt], 0, 0, 0);
            #pragma unroll
            for (int mt = 0; mt < 2; ++mt)
                #pragma unroll
                for (int nt = 0; nt < 2; ++nt)
                    acc[mt][nt] = __builtin_amdgcn_mfma_f32_16x16x32_bf16(ah[mt], bl[nt], acc[mt][nt], 0, 0, 0);
            #pragma unroll
            for (int mt = 0; mt < 2; ++mt)
                #pragma unroll
                for (int nt = 0; nt < 2; ++nt)
                    acc[mt][nt] = __builtin_amdgcn_mfma_f32_16x16x32_bf16(al_[mt], bh[nt], acc[mt][nt], 0, 0, 0);
            #pragma unroll
            for (int mt = 0; mt < 2; ++mt)
                #pragma unroll
                for (int nt = 0; nt < 2; ++nt)
                    acc[mt][nt] = __builtin_amdgcn_mfma_f32_16x16x32_bf16(al_[mt], bl[nt], acc[mt][nt], 0, 0, 0);
        }
        __syncthreads();                 // reads done before next staging write
    }

    // ---- epilogue: acc -> sL[32][132]  (C/D: col=lane&15, row=(lane>>4)*4+reg) ----
    #pragma unroll
    for (int mt = 0; mt < 2; ++mt)
        #pragma unroll
        for (int nt = 0; nt < 2; ++nt)
            #pragma unroll
            for (int r = 0; r < 4; ++r)
                sL[(mt * 16 + lg4 * 4 + r) * 132 + (w * 32 + nt * 16 + lr)] = acc[mt][nt][r];
    __syncthreads();

    // ---- gating: 4 waves x 8 rows, lane = expert ----
    float pacc = 0.f, zacc = 0.f;
    #pragma unroll 1
    for (int rr = 0; rr < 8; ++rr) {
        const int r = w * 8 + rr;
        const int grow = row0 + r;
        float lg   = sL[r * 132 + l] + bg[l];
        float npre = sL[r * 132 + 64 + l];
        float vcur = fmaf(noise[(size_t)grow * NE + l], softplusf(npre), lg);

        float tkv[9]; int tki[9];
        #pragma unroll
        for (int k = 0; k < 9; ++k) {
            float mv = vcur; int mi = l;
            #pragma unroll
            for (int o = 32; o > 0; o >>= 1) {
                float ov = __shfl_xor(mv, o);
                int   oi = __shfl_xor(mi, o);
                if (ov > mv || (ov == mv && oi < mi)) { mv = ov; mi = oi; }
            }
            tkv[k] = mv; tki[k] = mi;
            if (l == mi) vcur = -1e30f;
        }

        float m0 = tkv[0], s = 0.f, wk[TOPK];
        #pragma unroll
        for (int k = 0; k < TOPK; ++k) { wk[k] = expf(tkv[k] - m0); s += wk[k]; }
        float inv = 1.f / s;
        float myw = 0.f; int myi = 0;
        #pragma unroll
        for (int k = 0; k < TOPK; ++k)
            if (l == k) { myw = wk[k] * inv; myi = tki[k]; }
        if (l < TOPK) {
            out_w[(size_t)grow * TOPK + l] = myw;
            out_i[(size_t)grow * TOPK + l] = (float)myi;
        }

        if (l == 0) {
            atomicAdd(&sF[tki[0]], 1.f);
            float ming = 1e30f;
            #pragma unroll
            for (int k = 0; k < 8; ++k) ming = fminf(ming, tkv[k] - tkv[k + 1]);
            if (ming < TAU) {
                int slot = atomicAdd((int*)&ws[WS_CNT], 1);
                if (slot < listCap) ((int*)ws)[WS_LIST + slot] = grow;
            }
        }

        float rm = lg;
        #pragma unroll
        for (int o = 32; o > 0; o >>= 1) rm = fmaxf(rm, __shfl_xor(rm, o));
        float pe = expf(lg - rm);
        float ssum = pe;
        #pragma unroll
        for (int o = 32; o > 0; o >>= 1) ssum += __shfl_xor(ssum, o);
        pacc += pe / ssum;
        if (l == 0) { float lse = rm + logf(ssum); zacc += lse * lse; }
    }

    atomicAdd(&sP[l], pacc);
    if (l == 0) atomicAdd(sZ, zacc);
    __syncthreads();
    if (u < NE) {
        atomicAdd(&ws[u],      sF[u]);
        atomicAdd(&ws[NE + u], sP[u]);
    }
    if (u == 0) atomicAdd(&ws[2 * NE], sZ[0]);
}

// ---------------- pass 2: finalize scalars (block 0) + fp64 recheck of flagged rows ----------------
__global__ __launch_bounds__(256) void recheck_finalize_kernel(
    const float* __restrict__ x, const float* __restrict__ noise,
    const float* __restrict__ Wg, const float* __restrict__ bg,
    const float* __restrict__ Wn,
    float* __restrict__ out_w, float* __restrict__ out_i, float* __restrict__ out_s,
    const float* __restrict__ ws, int listCap)
{
    __shared__ double sRed[256 * 4];
    const int t = threadIdx.x;

    if (blockIdx.x == 0 && t < 64) {     // finalize (no barriers inside)
        float v = (ws[t] / (float)NB) * (ws[NE + t] / (float)NB);
        #pragma unroll
        for (int o = 32; o > 0; o >>= 1) v += __shfl_down(v, o);
        if (t == 0) {
            out_s[0] = (float)NE * v;
            out_s[1] = ws[2 * NE] / (float)NB;
        }
    }

    const int* wsi = (const int*)ws;
    int cnt = wsi[WS_CNT];
    if (cnt > listCap) cnt = listCap;
    if (cnt <= 0) return;

    const int e128 = t & 127;            // 0..63: Wg expert; 64..127: Wn expert-64
    const int half = t >> 7;             // K half
    const float* wr = (e128 < 64) ? (Wg + (size_t)e128 * IDIM)
                                  : (Wn + (size_t)(e128 - 64) * IDIM);
    wr += half * 1024;

    for (int base = blockIdx.x * 4; base < cnt; base += gridDim.x * 4) {
        int rows[4];
        #pragma unroll
        for (int i = 0; i < 4; ++i) {
            int ii = base + i;
            rows[i] = wsi[WS_LIST + (ii < cnt ? ii : cnt - 1)];
        }
        const float* xr0 = x + (size_t)rows[0] * IDIM + half * 1024;
        const float* xr1 = x + (size_t)rows[1] * IDIM + half * 1024;
        const float* xr2 = x + (size_t)rows[2] * IDIM + half * 1024;
        const float* xr3 = x + (size_t)rows[3] * IDIM + half * 1024;

        double a0 = 0, a1 = 0, a2 = 0, a3 = 0;
        for (int k = 0; k < 1024; k += 4) {
            float4 wv = *(const float4*)(wr + k);
            float4 x0 = *(const float4*)(xr0 + k);
            float4 x1 = *(const float4*)(xr1 + k);
            float4 x2 = *(const float4*)(xr2 + k);
            float4 x3 = *(const float4*)(xr3 + k);
            #pragma unroll
            for (int q = 0; q < 4; ++q) {
                double wd = (double)((float*)&wv)[q];
                a0 = fma((double)((float*)&x0)[q], wd, a0);
                a1 = fma((double)((float*)&x1)[q], wd, a1);
                a2 = fma((double)((float*)&x2)[q], wd, a2);
                a3 = fma((double)((float*)&x3)[q], wd, a3);
            }
        }
        sRed[t * 4 + 0] = a0; sRed[t * 4 + 1] = a1;
        sRed[t * 4 + 2] = a2; sRed[t * 4 + 3] = a3;
        __syncthreads();
        if (t < 128) {
            #pragma unroll
            for (int i = 0; i < 4; ++i) sRed[t * 4 + i] += sRed[(t + 128) * 4 + i];
        }
        __syncthreads();
        if (t < 64) {
            const int lane = t;
            double bgl = (double)bg[lane];
            #pragma unroll 1
            for (int i = 0; i < 4; ++i) {
                int row = rows[i];
                double g = sRed[lane * 4 + i];
                double n = sRed[(64 + lane) * 4 + i];
                double lgd = g + bgl;
                double nz = (double)noise[(size_t)row * NE + lane];
                double vcur = fma(nz, softplus_d(n), lgd);

                double tkv[TOPK]; int tki[TOPK];
                #pragma unroll
                for (int k = 0; k < TOPK; ++k) {
                    double mv = vcur; int mi = lane;
                    #pragma unroll
                    for (int o = 32; o > 0; o >>= 1) {
                        double ov = __shfl_xor(mv, o);
                        int    oi = __shfl_xor(mi, o);
                        if (ov > mv || (ov == mv && oi < mi)) { mv = ov; mi = oi; }
                    }
                    tkv[k] = mv; tki[k] = mi;
                    if (lane == mi) vcur = -1e300;
                }
                double m0 = tkv[0], s = 0.0, wk[TOPK];
                #pragma unroll
                for (int k = 0; k < TOPK; ++k) { wk[k] = exp(tkv[k] - m0); s += wk[k]; }
                double inv = 1.0 / s;
                float myw = 0.f; int myi = 0;
                #pragma unroll
                for (int k = 0; k < TOPK; ++k)
                    if (lane == k) { myw = (float)(wk[k] * inv); myi = tki[k]; }
                if (lane < TOPK) {
                    out_w[(size_t)row * TOPK + lane] = myw;
                    out_i[(size_t)row * TOPK + lane] = (float)myi;
                }
            }
        }
        __syncthreads();
    }
}

extern "C" void kernel_launch(void* const* d_in, const int* in_sizes, int n_in,
                              void* d_out, int out_size, void* d_ws, size_t ws_size,
                              hipStream_t stream) {
    const float* x     = (const float*)d_in[0];
    const float* noise = (const float*)d_in[1];
    const float* Wg    = (const float*)d_in[2];
    const float* bg    = (const float*)d_in[3];
    const float* Wn    = (const float*)d_in[4];
    float* out = (float*)d_out;
    float* ws  = (float*)d_ws;

    long cap = (long)(ws_size / 4) - WS_LIST;
    int listCap = (int)(cap < 0 ? 0 : (cap > NB ? NB : cap));

    hipLaunchKernelGGL(init_ws_kernel, dim3(1), dim3(256), 0, stream, ws);
    hipLaunchKernelGGL(gate_main_kernel, dim3(NB / BM), dim3(256), 0, stream,
                       x, noise, Wg, bg, Wn,
                       out, out + (size_t)NB * TOPK, ws, listCap);
    hipLaunchKernelGGL(recheck_finalize_kernel, dim3(256), dim3(256), 0, stream,
                       x, noise, Wg, bg, Wn,
                       out, out + (size_t)NB * TOPK, out + 2 * (size_t)NB * TOPK,
                       ws, listCap);
}

// Round 7
// 184.922 us; speedup vs baseline: 1.8766x; 1.1895x over previous
//
#include <hip/hip_runtime.h>
#include <math.h>

#define IDIM 2048
#define NE   64
#define TOPK 8
#define NB   16384
#define BM   32            // rows per block
#define BK   64            // k per chunk
#define NCH  (IDIM / BK)   // 32 chunks
#define TAU  5e-4f

// ws float layout: [0..63] f counts, [64..127] p sums, [128] z sum,
//                  [129] (int) flag count, [130..130+NB) (int) flagged row list
// byte WSPLIT_BYTE..: pre-split W tiles (32 tiles x (16KB hi + 16KB lo))
#define WS_CNT 129
#define WS_LIST 130
#define WSPLIT_BYTE 66560
#define WSPLIT_REQ  (WSPLIT_BYTE + NCH * 32768)

typedef __attribute__((ext_vector_type(8))) short bf16x8_t;  // 8 bf16 = 4 VGPRs
typedef __attribute__((ext_vector_type(4))) float f32x4_t;   // MFMA acc

__device__ __forceinline__ float softplusf(float v) {
    return (v > 0.f) ? (v + log1pf(expf(-v))) : log1pf(expf(v));
}
__device__ __forceinline__ double softplus_d(double v) {
    return (v > 0.0) ? (v + log1p(exp(-v))) : log1p(exp(v));
}

// deterministic RNE fp32 -> bf16 bits
__device__ __forceinline__ short f2bf(float f) {
    unsigned u = __float_as_uint(f);
    unsigned r = (u + 0x7FFFu + ((u >> 16) & 1u)) >> 16;
    return (short)r;
}
__device__ __forceinline__ float bf2f(short s) {
    return __uint_as_float(((unsigned)(unsigned short)s) << 16);
}

__global__ void init_ws_kernel(float* ws) {
    int t = threadIdx.x;
    if (t < WS_LIST) ws[t] = 0.0f;
}

__device__ __forceinline__ void split8(const float4 v0, const float4 v1,
                                       bf16x8_t& H, bf16x8_t& L) {
    float fv[8] = {v0.x, v0.y, v0.z, v0.w, v1.x, v1.y, v1.z, v1.w};
    #pragma unroll
    for (int q = 0; q < 8; ++q) {
        short hb = f2bf(fv[q]);
        short lb = f2bf(fv[q] - bf2f(hb));
        H[q] = hb; L[q] = lb;
    }
}

__device__ __forceinline__ void cvt_slot(const float4 v0, const float4 v1,
                                         char* hiP, char* loP, int off) {
    bf16x8_t H, L;
    split8(v0, v1, H, L);
    *(bf16x8_t*)(hiP + off) = H;
    *(bf16x8_t*)(loP + off) = L;
}

// ---------------- pass 0b: pre-split W into swizzled LDS tile images ----------------
__global__ __launch_bounds__(256) void prep_kernel(
    const float* __restrict__ Wg, const float* __restrict__ Wn,
    char* __restrict__ wsW)
{
    int g = blockIdx.x * 256 + threadIdx.x;   // 0..32767
    int t = g >> 10, i = g & 1023;
    int row = i >> 3, wslot = i & 7;
    int kslot = wslot ^ (row & 7);
    const float* src = (row < 64 ? Wg + (size_t)row * IDIM
                                 : Wn + (size_t)(row - 64) * IDIM) + t * BK + kslot * 8;
    float4 v0 = *(const float4*)src;
    float4 v1 = *(const float4*)(src + 4);
    bf16x8_t H, L;
    split8(v0, v1, H, L);
    char* dst = wsW + (size_t)t * 32768;
    *(bf16x8_t*)(dst + i * 16)         = H;
    *(bf16x8_t*)(dst + 16384 + i * 16) = L;
}

// ---------------- pass 1: split-bf16 MFMA GEMM + gating + flag near-ties ----------------
// LDS bytes: AH@0 (4096) AL@4096 (4096) BH@8192 (16384) BL@24576 (16384)
//   epilogue alias: sL f32[32][132] @0 ; sP@40960 sF@41216 sZ@41472
template<bool PRE>
__global__ __launch_bounds__(512, 4) void gate_main_kernel(
    const float* __restrict__ x, const float* __restrict__ noise,
    const float* __restrict__ Wg, const float* __restrict__ bg,
    const float* __restrict__ Wn, const char* __restrict__ wsW,
    float* __restrict__ out_w, float* __restrict__ out_i,
    float* __restrict__ ws, int listCap)
{
    __shared__ char smem[41488] __attribute__((aligned(16)));
    char* AH = smem;
    char* AL = smem + 4096;
    char* BH = smem + 8192;
    char* BL = smem + 24576;
    float* sP = (float*)(smem + 40960);
    float* sF = (float*)(smem + 41216);
    float* sZ = (float*)(smem + 41472);
    float* sL = (float*)smem;            // [32][132] epilogue alias

    const int u   = threadIdx.x;
    const int w   = u >> 6;              // wave 0..7, owns cols [w*16, w*16+16)
    const int l   = u & 63;
    const int lr  = l & 15;
    const int lg4 = l >> 4;
    const int s7  = lr & 7;
    const int row0 = blockIdx.x * BM;

    if (u < NE) { sP[u] = 0.f; sF[u] = 0.f; }
    if (u == 0) sZ[0] = 0.f;

    // A staging: threads 0..255, one 8-float slot each
    const int ar  = (u >> 3) & 31;
    const int ac  = u & 7;
    const int aoff = ar * 128 + (((ac ^ (ar & 7)) & 7) << 4);
    const float* pa = x + (size_t)(row0 + ar) * IDIM + ac * 8;

    // fallback W staging: thread u handles Wg[br] and Wn[br] slot ac
    const int br  = u >> 3;              // 0..63
    const float* pg = Wg + (size_t)br * IDIM + ac * 8;
    const float* pn = Wn + (size_t)br * IDIM + ac * 8;
    const int woff = br * 128 + ((ac ^ (br & 7)) << 4);

    f32x4_t acc[2];
    #pragma unroll
    for (int mt = 0; mt < 2; ++mt) {
        f32x4_t z = {0.f, 0.f, 0.f, 0.f};
        acc[mt] = z;
    }

    float4 ra0, ra1;                 // x in-flight
    int4 w0, w1, w2, w3;             // PRE: W in-flight (pre-split)
    float4 g0, g1, n0, n1;           // !PRE: W floats in-flight

#define LOADT(tt) { const int k0 = (tt) * BK;                                   \
    if (u < 256) { ra0 = *(const float4*)(pa + k0);                             \
                   ra1 = *(const float4*)(pa + k0 + 4); }                       \
    if constexpr (PRE) {                                                        \
        const char* s_ = wsW + (size_t)(tt) * 32768 + u * 16;                   \
        w0 = *(const int4*)(s_);          w1 = *(const int4*)(s_ + 8192);       \
        w2 = *(const int4*)(s_ + 16384);  w3 = *(const int4*)(s_ + 24576);      \
    } else {                                                                    \
        g0 = *(const float4*)(pg + k0);   g1 = *(const float4*)(pg + k0 + 4);   \
        n0 = *(const float4*)(pn + k0);   n1 = *(const float4*)(pn + k0 + 4);   \
    } }

    LOADT(0);

    for (int t = 0; t < NCH; ++t) {
        __syncthreads();                 // previous tile's LDS reads complete
        if (u < 256) cvt_slot(ra0, ra1, AH, AL, aoff);
        if constexpr (PRE) {
            *(int4*)(BH + u * 16)        = w0;
            *(int4*)(BH + 8192 + u * 16) = w1;
            *(int4*)(BL + u * 16)        = w2;
            *(int4*)(BL + 8192 + u * 16) = w3;
        } else {
            cvt_slot(g0, g1, BH, BL, woff);
            cvt_slot(n0, n1, BH, BL, woff + 8192);
        }
        if (t + 1 < NCH) LOADT(t + 1);   // next-tile loads land during compute
        __syncthreads();                 // staging visible

        #pragma unroll
        for (int ks = 0; ks < 2; ++ks) {
            const int so = (((ks * 4 + lg4) ^ s7) << 4);
            bf16x8_t ah[2], al_[2], bh, bl;
            #pragma unroll
            for (int mt = 0; mt < 2; ++mt) {
                const int o = (mt * 16 + lr) * 128 + so;
                ah[mt]  = *(const bf16x8_t*)(AH + o);
                al_[mt] = *(const bf16x8_t*)(AL + o);
            }
            {
                const int o = (w * 16 + lr) * 128 + so;
                bh = *(const bf16x8_t*)(BH + o);
                bl = *(const bf16x8_t*)(BL + o);
            }
            #pragma unroll
            for (int mt = 0; mt < 2; ++mt) {
                acc[mt] = __builtin_amdgcn_mfma_f32_16x16x32_bf16(ah[mt],  bh, acc[mt], 0, 0, 0);
                acc[mt] = __builtin_amdgcn_mfma_f32_16x16x32_bf16(ah[mt],  bl, acc[mt], 0, 0, 0);
                acc[mt] = __builtin_amdgcn_mfma_f32_16x16x32_bf16(al_[mt], bh, acc[mt], 0, 0, 0);
            }
        }
    }
    __syncthreads();   // staging dead; safe to alias

    // ---- epilogue: acc -> sL[32][132]  (C/D: col=lane&15, row=(lane>>4)*4+reg) ----
    #pragma unroll
    for (int mt = 0; mt < 2; ++mt)
        #pragma unroll
        for (int r = 0; r < 4; ++r)
            sL[(mt * 16 + lg4 * 4 + r) * 132 + (w * 16 + lr)] = acc[mt][r];
    __syncthreads();

    // ---- gating: 8 waves x 4 rows, lane = expert ----
    float pacc = 0.f, zacc = 0.f;
    #pragma unroll 1
    for (int rr = 0; rr < 4; ++rr) {
        const int r = w * 4 + rr;
        const int grow = row0 + r;
        float lg   = sL[r * 132 + l] + bg[l];
        float npre = sL[r * 132 + 64 + l];
        float vcur = fmaf(noise[(size_t)grow * NE + l], softplusf(npre), lg);

        float tkv[9]; int tki[9];
        #pragma unroll
        for (int k = 0; k < 9; ++k) {
            float mv = vcur; int mi = l;
            #pragma unroll
            for (int o = 32; o > 0; o >>= 1) {
                float ov = __shfl_xor(mv, o);
                int   oi = __shfl_xor(mi, o);
                if (ov > mv || (ov == mv && oi < mi)) { mv = ov; mi = oi; }
            }
            tkv[k] = mv; tki[k] = mi;
            if (l == mi) vcur = -1e30f;
        }

        float m0 = tkv[0], s = 0.f, wk[TOPK];
        #pragma unroll
        for (int k = 0; k < TOPK; ++k) { wk[k] = expf(tkv[k] - m0); s += wk[k]; }
        float inv = 1.f / s;
        float myw = 0.f; int myi = 0;
        #pragma unroll
        for (int k = 0; k < TOPK; ++k)
            if (l == k) { myw = wk[k] * inv; myi = tki[k]; }
        if (l < TOPK) {
            out_w[(size_t)grow * TOPK + l] = myw;
            out_i[(size_t)grow * TOPK + l] = (float)myi;
        }

        if (l == 0) {
            atomicAdd(&sF[tki[0]], 1.f);
            float ming = 1e30f;
            #pragma unroll
            for (int k = 0; k < 8; ++k) ming = fminf(ming, tkv[k] - tkv[k + 1]);
            if (ming < TAU) {
                int slot = atomicAdd((int*)&ws[WS_CNT], 1);
                if (slot < listCap) ((int*)ws)[WS_LIST + slot] = grow;
            }
        }

        float rm = lg;
        #pragma unroll
        for (int o = 32; o > 0; o >>= 1) rm = fmaxf(rm, __shfl_xor(rm, o));
        float pe = expf(lg - rm);
        float ssum = pe;
        #pragma unroll
        for (int o = 32; o > 0; o >>= 1) ssum += __shfl_xor(ssum, o);
        pacc += pe / ssum;
        if (l == 0) { float lse = rm + logf(ssum); zacc += lse * lse; }
    }

    atomicAdd(&sP[l], pacc);
    if (l == 0) atomicAdd(sZ, zacc);
    __syncthreads();
    if (u < NE) {
        atomicAdd(&ws[u],      sF[u]);
        atomicAdd(&ws[NE + u], sP[u]);
    }
    if (u == 0) atomicAdd(&ws[2 * NE], sZ[0]);
}

// ---------------- pass 2: finalize scalars (block 0) + fp64 recheck of flagged rows ----------------
__global__ __launch_bounds__(256) void recheck_finalize_kernel(
    const float* __restrict__ x, const float* __restrict__ noise,
    const float* __restrict__ Wg, const float* __restrict__ bg,
    const float* __restrict__ Wn,
    float* __restrict__ out_w, float* __restrict__ out_i, float* __restrict__ out_s,
    const float* __restrict__ ws, int listCap)
{
    __shared__ double sRed[256 * 4];
    const int t = threadIdx.x;

    if (blockIdx.x == 0 && t < 64) {
        float v = (ws[t] / (float)NB) * (ws[NE + t] / (float)NB);
        #pragma unroll
        for (int o = 32; o > 0; o >>= 1) v += __shfl_down(v, o);
        if (t == 0) {
            out_s[0] = (float)NE * v;
            out_s[1] = ws[2 * NE] / (float)NB;
        }
    }

    const int* wsi = (const int*)ws;
    int cnt = wsi[WS_CNT];
    if (cnt > listCap) cnt = listCap;
    if (cnt <= 0) return;

    const int e128 = t & 127;
    const int half = t >> 7;
    const float* wr = (e128 < 64) ? (Wg + (size_t)e128 * IDIM)
                                  : (Wn + (size_t)(e128 - 64) * IDIM);
    wr += half * 1024;

    for (int base = blockIdx.x * 4; base < cnt; base += gridDim.x * 4) {
        int rows[4];
        #pragma unroll
        for (int i = 0; i < 4; ++i) {
            int ii = base + i;
            rows[i] = wsi[WS_LIST + (ii < cnt ? ii : cnt - 1)];
        }
        const float* xr0 = x + (size_t)rows[0] * IDIM + half * 1024;
        const float* xr1 = x + (size_t)rows[1] * IDIM + half * 1024;
        const float* xr2 = x + (size_t)rows[2] * IDIM + half * 1024;
        const float* xr3 = x + (size_t)rows[3] * IDIM + half * 1024;

        double a0 = 0, a1 = 0, a2 = 0, a3 = 0;
        for (int k = 0; k < 1024; k += 4) {
            float4 wv = *(const float4*)(wr + k);
            float4 x0 = *(const float4*)(xr0 + k);
            float4 x1 = *(const float4*)(xr1 + k);
            float4 x2 = *(const float4*)(xr2 + k);
            float4 x3 = *(const float4*)(xr3 + k);
            #pragma unroll
            for (int q = 0; q < 4; ++q) {
                double wd = (double)((float*)&wv)[q];
                a0 = fma((double)((float*)&x0)[q], wd, a0);
                a1 = fma((double)((float*)&x1)[q], wd, a1);
                a2 = fma((double)((float*)&x2)[q], wd, a2);
                a3 = fma((double)((float*)&x3)[q], wd, a3);
            }
        }
        sRed[t * 4 + 0] = a0; sRed[t * 4 + 1] = a1;
        sRed[t * 4 + 2] = a2; sRed[t * 4 + 3] = a3;
        __syncthreads();
        if (t < 128) {
            #pragma unroll
            for (int i = 0; i < 4; ++i) sRed[t * 4 + i] += sRed[(t + 128) * 4 + i];
        }
        __syncthreads();
        if (t < 64) {
            const int lane = t;
            double bgl = (double)bg[lane];
            #pragma unroll 1
            for (int i = 0; i < 4; ++i) {
                int row = rows[i];
                double g = sRed[lane * 4 + i];
                double n = sRed[(64 + lane) * 4 + i];
                double lgd = g + bgl;
                double nz = (double)noise[(size_t)row * NE + lane];
                double vcur = fma(nz, softplus_d(n), lgd);

                double tkv[TOPK]; int tki[TOPK];
                #pragma unroll
                for (int k = 0; k < TOPK; ++k) {
                    double mv = vcur; int mi = lane;
                    #pragma unroll
                    for (int o = 32; o > 0; o >>= 1) {
                        double ov = __shfl_xor(mv, o);
                        int    oi = __shfl_xor(mi, o);
                        if (ov > mv || (ov == mv && oi < mi)) { mv = ov; mi = oi; }
                    }
                    tkv[k] = mv; tki[k] = mi;
                    if (lane == mi) vcur = -1e300;
                }
                double m0 = tkv[0], s = 0.0, wk[TOPK];
                #pragma unroll
                for (int k = 0; k < TOPK; ++k) { wk[k] = exp(tkv[k] - m0); s += wk[k]; }
                double inv = 1.0 / s;
                float myw = 0.f; int myi = 0;
                #pragma unroll
                for (int k = 0; k < TOPK; ++k)
                    if (lane == k) { myw = (float)(wk[k] * inv); myi = tki[k]; }
                if (lane < TOPK) {
                    out_w[(size_t)row * TOPK + lane] = myw;
                    out_i[(size_t)row * TOPK + lane] = (float)myi;
                }
            }
        }
        __syncthreads();
    }
}

extern "C" void kernel_launch(void* const* d_in, const int* in_sizes, int n_in,
                              void* d_out, int out_size, void* d_ws, size_t ws_size,
                              hipStream_t stream) {
    const float* x     = (const float*)d_in[0];
    const float* noise = (const float*)d_in[1];
    const float* Wg    = (const float*)d_in[2];
    const float* bg    = (const float*)d_in[3];
    const float* Wn    = (const float*)d_in[4];
    float* out = (float*)d_out;
    float* ws  = (float*)d_ws;
    char*  wsW = (char*)d_ws + WSPLIT_BYTE;

    long cap = (long)(ws_size / 4) - WS_LIST;
    int listCap = (int)(cap < 0 ? 0 : (cap > NB ? NB : cap));
    const bool pre = ws_size >= (size_t)WSPLIT_REQ;

    hipLaunchKernelGGL(init_ws_kernel, dim3(1), dim3(256), 0, stream, ws);
    if (pre) {
        hipLaunchKernelGGL(prep_kernel, dim3(128), dim3(256), 0, stream, Wg, Wn, wsW);
        hipLaunchKernelGGL(gate_main_kernel<true>, dim3(NB / BM), dim3(512), 0, stream,
                           x, noise, Wg, bg, Wn, wsW,
                           out, out + (size_t)NB * TOPK, ws, listCap);
    } else {
        hipLaunchKernelGGL(gate_main_kernel<false>, dim3(NB / BM), dim3(512), 0, stream,
                           x, noise, Wg, bg, Wn, wsW,
                           out, out + (size_t)NB * TOPK, ws, listCap);
    }
    hipLaunchKernelGGL(recheck_finalize_kernel, dim3(256), dim3(256), 0, stream,
                       x, noise, Wg, bg, Wn,
                       out, out + (size_t)NB * TOPK, out + 2 * (size_t)NB * TOPK,
                       ws, listCap);
}

// Round 8
// 170.777 us; speedup vs baseline: 2.0320x; 1.0828x over previous
//
#include <hip/hip_runtime.h>
#include <math.h>

#define IDIM 2048
#define NE   64
#define TOPK 8
#define NB   16384
#define BM   32            // rows per block
#define BK   64            // k per chunk
#define NCH  (IDIM / BK)   // 32 chunks
#define TAU  5e-4f

// ws float layout: [0..63] f counts, [64..127] p sums, [128] z sum,
//                  [129] (int) flag count, [130..130+NB) (int) flagged row list
// byte WSPLIT_BYTE..: pre-split W tiles (32 tiles x (16KB hi + 16KB lo))
#define WS_CNT 129
#define WS_LIST 130
#define WSPLIT_BYTE 66560
#define WSPLIT_REQ  (WSPLIT_BYTE + NCH * 32768)

typedef __attribute__((ext_vector_type(8))) short bf16x8_t;  // 8 bf16 = 4 VGPRs
typedef __attribute__((ext_vector_type(4))) float f32x4_t;   // MFMA acc

__device__ __forceinline__ float softplusf(float v) {
    return (v > 0.f) ? (v + log1pf(expf(-v))) : log1pf(expf(v));
}
__device__ __forceinline__ double softplus_d(double v) {
    return (v > 0.0) ? (v + log1p(exp(-v))) : log1p(exp(v));
}

// deterministic RNE fp32 -> bf16 bits
__device__ __forceinline__ short f2bf(float f) {
    unsigned u = __float_as_uint(f);
    unsigned r = (u + 0x7FFFu + ((u >> 16) & 1u)) >> 16;
    return (short)r;
}
__device__ __forceinline__ float bf2f(short s) {
    return __uint_as_float(((unsigned)(unsigned short)s) << 16);
}

__global__ void init_ws_kernel(float* ws) {
    int t = threadIdx.x;
    if (t < WS_LIST) ws[t] = 0.0f;
}

__device__ __forceinline__ void split8(const float4 v0, const float4 v1,
                                       bf16x8_t& H, bf16x8_t& L) {
    float fv[8] = {v0.x, v0.y, v0.z, v0.w, v1.x, v1.y, v1.z, v1.w};
    #pragma unroll
    for (int q = 0; q < 8; ++q) {
        short hb = f2bf(fv[q]);
        short lb = f2bf(fv[q] - bf2f(hb));
        H[q] = hb; L[q] = lb;
    }
}

__device__ __forceinline__ void cvt_slot(const float4 v0, const float4 v1,
                                         char* hiP, char* loP, int off) {
    bf16x8_t H, L;
    split8(v0, v1, H, L);
    *(bf16x8_t*)(hiP + off) = H;
    *(bf16x8_t*)(loP + off) = L;
}

// ---------------- pass 0b: pre-split W into swizzled LDS tile images ----------------
__global__ __launch_bounds__(256) void prep_kernel(
    const float* __restrict__ Wg, const float* __restrict__ Wn,
    char* __restrict__ wsW)
{
    int g = blockIdx.x * 256 + threadIdx.x;   // 0..32767
    int t = g >> 10, i = g & 1023;
    int row = i >> 3, wslot = i & 7;
    int kslot = wslot ^ (row & 7);
    const float* src = (row < 64 ? Wg + (size_t)row * IDIM
                                 : Wn + (size_t)(row - 64) * IDIM) + t * BK + kslot * 8;
    float4 v0 = *(const float4*)src;
    float4 v1 = *(const float4*)(src + 4);
    bf16x8_t H, L;
    split8(v0, v1, H, L);
    char* dst = wsW + (size_t)t * 32768;
    *(bf16x8_t*)(dst + i * 16)         = H;
    *(bf16x8_t*)(dst + 16384 + i * 16) = L;
}

// ---------------- pass 1: split-bf16 MFMA GEMM + gating + flag near-ties ----------------
// LDS bytes: AH@0 (4096) AL@4096 (4096) BH@8192 (16384) BL@24576 (16384)
//   epilogue alias: sL f32[32][132] @0 ; sP@40960 sF@41216 sZ@41472
template<bool PRE>
__global__ __launch_bounds__(512, 4) void gate_main_kernel(
    const float* __restrict__ x, const float* __restrict__ noise,
    const float* __restrict__ Wg, const float* __restrict__ bg,
    const float* __restrict__ Wn, const char* __restrict__ wsW,
    float* __restrict__ out_w, float* __restrict__ out_i,
    float* __restrict__ ws, int listCap)
{
    __shared__ char smem[41488] __attribute__((aligned(16)));
    char* AH = smem;
    char* AL = smem + 4096;
    char* BH = smem + 8192;
    char* BL = smem + 24576;
    float* sP = (float*)(smem + 40960);
    float* sF = (float*)(smem + 41216);
    float* sZ = (float*)(smem + 41472);
    float* sL = (float*)smem;            // [32][132] epilogue alias

    const int u   = threadIdx.x;
    const int w   = u >> 6;              // wave 0..7, owns cols [w*16, w*16+16)
    const int l   = u & 63;
    const int lr  = l & 15;
    const int lg4 = l >> 4;
    const int s7  = lr & 7;
    const int row0 = blockIdx.x * BM;

    if (u < NE) { sP[u] = 0.f; sF[u] = 0.f; }
    if (u == 0) sZ[0] = 0.f;

    // A staging: threads 0..255, one 8-float slot each
    const int ar  = (u >> 3) & 31;
    const int ac  = u & 7;
    const int aoff = ar * 128 + (((ac ^ (ar & 7)) & 7) << 4);
    const float* pa = x + (size_t)(row0 + ar) * IDIM + ac * 8;

    // fallback W staging: thread u handles Wg[br] and Wn[br] slot ac
    const int br  = u >> 3;              // 0..63
    const float* pg = Wg + (size_t)br * IDIM + ac * 8;
    const float* pn = Wn + (size_t)br * IDIM + ac * 8;
    const int woff = br * 128 + ((ac ^ (br & 7)) << 4);

    f32x4_t acc[2];
    #pragma unroll
    for (int mt = 0; mt < 2; ++mt) {
        f32x4_t z = {0.f, 0.f, 0.f, 0.f};
        acc[mt] = z;
    }

    float4 ra0, ra1;                 // x in-flight
    int4 w0, w1, w2, w3;             // PRE: W in-flight (pre-split)
    float4 g0, g1, n0, n1;           // !PRE: W floats in-flight

#define LOADT(tt) { const int k0 = (tt) * BK;                                   \
    if (u < 256) { ra0 = *(const float4*)(pa + k0);                             \
                   ra1 = *(const float4*)(pa + k0 + 4); }                       \
    if constexpr (PRE) {                                                        \
        const char* s_ = wsW + (size_t)(tt) * 32768 + u * 16;                   \
        w0 = *(const int4*)(s_);          w1 = *(const int4*)(s_ + 8192);       \
        w2 = *(const int4*)(s_ + 16384);  w3 = *(const int4*)(s_ + 24576);      \
    } else {                                                                    \
        g0 = *(const float4*)(pg + k0);   g1 = *(const float4*)(pg + k0 + 4);   \
        n0 = *(const float4*)(pn + k0);   n1 = *(const float4*)(pn + k0 + 4);   \
    } }

    LOADT(0);

    for (int t = 0; t < NCH; ++t) {
        __syncthreads();                 // previous tile's LDS reads complete
        if (u < 256) cvt_slot(ra0, ra1, AH, AL, aoff);
        if constexpr (PRE) {
            *(int4*)(BH + u * 16)        = w0;
            *(int4*)(BH + 8192 + u * 16) = w1;
            *(int4*)(BL + u * 16)        = w2;
            *(int4*)(BL + 8192 + u * 16) = w3;
        } else {
            cvt_slot(g0, g1, BH, BL, woff);
            cvt_slot(n0, n1, BH, BL, woff + 8192);
        }
        if (t + 1 < NCH) LOADT(t + 1);   // next-tile loads land during compute
        __syncthreads();                 // staging visible

        #pragma unroll
        for (int ks = 0; ks < 2; ++ks) {
            const int so = (((ks * 4 + lg4) ^ s7) << 4);
            bf16x8_t ah[2], al_[2], bh, bl;
            #pragma unroll
            for (int mt = 0; mt < 2; ++mt) {
                const int o = (mt * 16 + lr) * 128 + so;
                ah[mt]  = *(const bf16x8_t*)(AH + o);
                al_[mt] = *(const bf16x8_t*)(AL + o);
            }
            {
                const int o = (w * 16 + lr) * 128 + so;
                bh = *(const bf16x8_t*)(BH + o);
                bl = *(const bf16x8_t*)(BL + o);
            }
            #pragma unroll
            for (int mt = 0; mt < 2; ++mt) {
                acc[mt] = __builtin_amdgcn_mfma_f32_16x16x32_bf16(ah[mt],  bh, acc[mt], 0, 0, 0);
                acc[mt] = __builtin_amdgcn_mfma_f32_16x16x32_bf16(ah[mt],  bl, acc[mt], 0, 0, 0);
                acc[mt] = __builtin_amdgcn_mfma_f32_16x16x32_bf16(al_[mt], bh, acc[mt], 0, 0, 0);
            }
        }
    }
    __syncthreads();   // staging dead; safe to alias

    // ---- epilogue: acc -> sL[32][132]  (C/D: col=lane&15, row=(lane>>4)*4+reg) ----
    #pragma unroll
    for (int mt = 0; mt < 2; ++mt)
        #pragma unroll
        for (int r = 0; r < 4; ++r)
            sL[(mt * 16 + lg4 * 4 + r) * 132 + (w * 16 + lr)] = acc[mt][r];
    __syncthreads();

    // ---- gating: 8 waves x 4 rows, lane = expert ----
    float pacc = 0.f, zacc = 0.f;
    #pragma unroll 1
    for (int rr = 0; rr < 4; ++rr) {
        const int r = w * 4 + rr;
        const int grow = row0 + r;
        float lg   = sL[r * 132 + l] + bg[l];
        float npre = sL[r * 132 + 64 + l];
        float vcur = fmaf(noise[(size_t)grow * NE + l], softplusf(npre), lg);

        float tkv[9]; int tki[9];
        #pragma unroll
        for (int k = 0; k < 9; ++k) {
            float mv = vcur; int mi = l;
            #pragma unroll
            for (int o = 32; o > 0; o >>= 1) {
                float ov = __shfl_xor(mv, o);
                int   oi = __shfl_xor(mi, o);
                if (ov > mv || (ov == mv && oi < mi)) { mv = ov; mi = oi; }
            }
            tkv[k] = mv; tki[k] = mi;
            if (l == mi) vcur = -1e30f;
        }

        float m0 = tkv[0], s = 0.f, wk[TOPK];
        #pragma unroll
        for (int k = 0; k < TOPK; ++k) { wk[k] = expf(tkv[k] - m0); s += wk[k]; }
        float inv = 1.f / s;
        float myw = 0.f; int myi = 0;
        #pragma unroll
        for (int k = 0; k < TOPK; ++k)
            if (l == k) { myw = wk[k] * inv; myi = tki[k]; }
        if (l < TOPK) {
            out_w[(size_t)grow * TOPK + l] = myw;
            out_i[(size_t)grow * TOPK + l] = (float)myi;
        }

        if (l == 0) {
            atomicAdd(&sF[tki[0]], 1.f);
            float ming = 1e30f;
            #pragma unroll
            for (int k = 0; k < 8; ++k) ming = fminf(ming, tkv[k] - tkv[k + 1]);
            if (ming < TAU) {
                int slot = atomicAdd((int*)&ws[WS_CNT], 1);
                if (slot < listCap) ((int*)ws)[WS_LIST + slot] = grow;
            }
        }

        float rm = lg;
        #pragma unroll
        for (int o = 32; o > 0; o >>= 1) rm = fmaxf(rm, __shfl_xor(rm, o));
        float pe = expf(lg - rm);
        float ssum = pe;
        #pragma unroll
        for (int o = 32; o > 0; o >>= 1) ssum += __shfl_xor(ssum, o);
        pacc += pe / ssum;
        if (l == 0) { float lse = rm + logf(ssum); zacc += lse * lse; }
    }

    atomicAdd(&sP[l], pacc);
    if (l == 0) atomicAdd(sZ, zacc);
    __syncthreads();
    if (u < NE) {
        atomicAdd(&ws[u],      sF[u]);
        atomicAdd(&ws[NE + u], sP[u]);
    }
    if (u == 0) atomicAdd(&ws[2 * NE], sZ[0]);
}

// ---------------- pass 2: finalize scalars (block 0) + fp64 recheck, 1 row/block ----------------
// 512 threads = 128 dot-slots (0..63 Wg expert, 64..127 Wn expert) x 4 K-quarters.
__global__ __launch_bounds__(512) void recheck_finalize_kernel(
    const float* __restrict__ x, const float* __restrict__ noise,
    const float* __restrict__ Wg, const float* __restrict__ bg,
    const float* __restrict__ Wn,
    float* __restrict__ out_w, float* __restrict__ out_i, float* __restrict__ out_s,
    const float* __restrict__ ws, int listCap)
{
    __shared__ double sRed[512];
    const int t = threadIdx.x;

    if (blockIdx.x == 0 && t < 64) {     // finalize scalars (wave 0, no barriers)
        float v = (ws[t] / (float)NB) * (ws[NE + t] / (float)NB);
        #pragma unroll
        for (int o = 32; o > 0; o >>= 1) v += __shfl_down(v, o);
        if (t == 0) {
            out_s[0] = (float)NE * v;
            out_s[1] = ws[2 * NE] / (float)NB;
        }
    }

    const int* wsi = (const int*)ws;
    int cnt = wsi[WS_CNT];
    if (cnt > listCap) cnt = listCap;
    if (cnt <= 0) return;

    const int slot = t & 127;            // 0..63: Wg expert; 64..127: Wn expert-64
    const int q4   = t >> 7;             // K quarter: [q4*512, +512)
    const float* wrb = ((slot < 64) ? (Wg + (size_t)slot * IDIM)
                                    : (Wn + (size_t)(slot - 64) * IDIM)) + q4 * 512;

    for (int bi = blockIdx.x; bi < cnt; bi += gridDim.x) {
        const int row = wsi[WS_LIST + bi];
        const float* xr = x + (size_t)row * IDIM + q4 * 512;

        double a = 0.0;
        #pragma unroll 4
        for (int k = 0; k < 512; k += 4) {
            float4 wv = *(const float4*)(wrb + k);
            float4 xv = *(const float4*)(xr + k);
            a = fma((double)xv.x, (double)wv.x, a);
            a = fma((double)xv.y, (double)wv.y, a);
            a = fma((double)xv.z, (double)wv.z, a);
            a = fma((double)xv.w, (double)wv.w, a);
        }
        sRed[t] = a;
        __syncthreads();
        if (t < 128)
            sRed[t] = sRed[t] + sRed[t + 128] + sRed[t + 256] + sRed[t + 384];
        __syncthreads();

        if (t < 64) {
            const int lane = t;
            double g = sRed[lane];
            double n = sRed[64 + lane];
            double lgd = g + (double)bg[lane];
            double nz = (double)noise[(size_t)row * NE + lane];
            double vcur = fma(nz, softplus_d(n), lgd);

            double tkv[TOPK]; int tki[TOPK];
            #pragma unroll
            for (int k = 0; k < TOPK; ++k) {
                double mv = vcur; int mi = lane;
                #pragma unroll
                for (int o = 32; o > 0; o >>= 1) {
                    double ov = __shfl_xor(mv, o);
                    int    oi = __shfl_xor(mi, o);
                    if (ov > mv || (ov == mv && oi < mi)) { mv = ov; mi = oi; }
                }
                tkv[k] = mv; tki[k] = mi;
                if (lane == mi) vcur = -1e300;
            }
            double m0 = tkv[0], s = 0.0, wk[TOPK];
            #pragma unroll
            for (int k = 0; k < TOPK; ++k) { wk[k] = exp(tkv[k] - m0); s += wk[k]; }
            double inv = 1.0 / s;
            float myw = 0.f; int myi = 0;
            #pragma unroll
            for (int k = 0; k < TOPK; ++k)
                if (lane == k) { myw = (float)(wk[k] * inv); myi = tki[k]; }
            if (lane < TOPK) {
                out_w[(size_t)row * TOPK + lane] = myw;
                out_i[(size_t)row * TOPK + lane] = (float)myi;
            }
        }
        __syncthreads();   // sRed reuse safe
    }
}

extern "C" void kernel_launch(void* const* d_in, const int* in_sizes, int n_in,
                              void* d_out, int out_size, void* d_ws, size_t ws_size,
                              hipStream_t stream) {
    const float* x     = (const float*)d_in[0];
    const float* noise = (const float*)d_in[1];
    const float* Wg    = (const float*)d_in[2];
    const float* bg    = (const float*)d_in[3];
    const float* Wn    = (const float*)d_in[4];
    float* out = (float*)d_out;
    float* ws  = (float*)d_ws;
    char*  wsW = (char*)d_ws + WSPLIT_BYTE;

    long cap = (long)(ws_size / 4) - WS_LIST;
    int listCap = (int)(cap < 0 ? 0 : (cap > NB ? NB : cap));
    const bool pre = ws_size >= (size_t)WSPLIT_REQ;

    hipLaunchKernelGGL(init_ws_kernel, dim3(1), dim3(256), 0, stream, ws);
    if (pre) {
        hipLaunchKernelGGL(prep_kernel, dim3(128), dim3(256), 0, stream, Wg, Wn, wsW);
        hipLaunchKernelGGL(gate_main_kernel<true>, dim3(NB / BM), dim3(512), 0, stream,
                           x, noise, Wg, bg, Wn, wsW,
                           out, out + (size_t)NB * TOPK, ws, listCap);
    } else {
        hipLaunchKernelGGL(gate_main_kernel<false>, dim3(NB / BM), dim3(512), 0, stream,
                           x, noise, Wg, bg, Wn, wsW,
                           out, out + (size_t)NB * TOPK, ws, listCap);
    }
    hipLaunchKernelGGL(recheck_finalize_kernel, dim3(1024), dim3(512), 0, stream,
                       x, noise, Wg, bg, Wn,
                       out, out + (size_t)NB * TOPK, out + 2 * (size_t)NB * TOPK,
                       ws, listCap);
}